// Round 4
// baseline (452.273 us; speedup 1.0000x reference)
//
#include <hip/hip_runtime.h>

#define TT 512
#define BB 1024
#define INV2PI 0.15915494309189535f
#define INV4PI 0.07957747154594767f

__device__ __forceinline__ float frcp(float x){ return __builtin_amdgcn_rcpf(x); }
__device__ __forceinline__ float fexp2(float x){ return __builtin_amdgcn_exp2f(x); }
// cos(2*pi*r) with r already in revolutions
__device__ __forceinline__ float fcosrev(float r){
  float rr = r - floorf(r);
  return __builtin_amdgcn_cosf(rr);
}

// DPP helpers (float through int). ror:n => lane l reads lane (l+16-n)%16.
#define DPPZ(v, ctrl) __int_as_float(__builtin_amdgcn_update_dpp(0, __float_as_int(v), (ctrl), 0xF, 0xF, true))
#define DPPR(v, ctrl) __int_as_float(__builtin_amdgcn_update_dpp(__float_as_int(v), __float_as_int(v), (ctrl), 0xF, 0xF, false))

// ---------------- Phase 1: xpre projection (pre-scaled to revolutions) ----
// xpre[t][b][c], c in [0,40):
//   c<32  (gate g=c>>3, jj=c&7):  (x@Wg[:64] + bg + thg) * INV2PI
//   c>=32 (kernel, jj=c-32):      (x@Wi2k + bi2k - bh2k) * INV4PI
__global__ __launch_bounds__(256) void qlstm_proj(
    const float* __restrict__ x,
    const float* __restrict__ Wf, const float* __restrict__ bf, const float* __restrict__ thf,
    const float* __restrict__ Wi, const float* __restrict__ bi, const float* __restrict__ thi,
    const float* __restrict__ Wu, const float* __restrict__ bu, const float* __restrict__ thu,
    const float* __restrict__ Wo, const float* __restrict__ bo, const float* __restrict__ tho,
    const float* __restrict__ bh2k,
    const float* __restrict__ Wi2k, const float* __restrict__ bi2k,
    float* __restrict__ buf)
{
  __shared__ float4 wl4[64][10];
  __shared__ float bias[40];
  int tid = threadIdx.x;
  float* wl = (float*)wl4;
  for (int idx = tid; idx < 64*40; idx += 256){
    int d = idx / 40, c = idx - d*40;
    float v;
    if (c < 32){
      int g = c >> 3, jj = c & 7;
      const float* W = (g==0)?Wf:((g==1)?Wi:((g==2)?Wu:Wo));
      v = W[d*8+jj] * INV2PI;
    } else {
      v = Wi2k[d*8 + (c-32)] * INV4PI;
    }
    wl[d*40+c] = v;
  }
  if (tid < 40){
    int c = tid; float v;
    if (c < 32){
      int g = c >> 3, jj = c & 7;
      const float* bp = (g==0)?bf:((g==1)?bi:((g==2)?bu:bo));
      const float* tp = (g==0)?thf:((g==1)?thi:((g==2)?thu:tho));
      v = (bp[jj] + tp[jj]) * INV2PI;
    } else {
      v = (bi2k[c-32] - bh2k[c-32]) * INV4PI;
    }
    bias[c] = v;
  }
  __syncthreads();

  long r0 = (long)blockIdx.x*512 + tid;
  long r1 = r0 + 256;
  const float4* x0 = (const float4*)(x + r0*64);
  const float4* x1 = (const float4*)(x + r1*64);
  float4 a0[10], a1[10];
#pragma unroll
  for (int q=0;q<10;++q){
    a0[q] = make_float4(bias[q*4+0],bias[q*4+1],bias[q*4+2],bias[q*4+3]);
    a1[q] = a0[q];
  }
#pragma unroll 1
  for (int d4=0; d4<16; ++d4){
    float4 xv0 = x0[d4];
    float4 xv1 = x1[d4];
#pragma unroll
    for (int dd=0; dd<4; ++dd){
      float s0 = (dd==0)?xv0.x:((dd==1)?xv0.y:((dd==2)?xv0.z:xv0.w));
      float s1 = (dd==0)?xv1.x:((dd==1)?xv1.y:((dd==2)?xv1.z:xv1.w));
#pragma unroll
      for (int q=0;q<10;++q){
        float4 wv = wl4[d4*4+dd][q];
        a0[q].x += s0*wv.x; a0[q].y += s0*wv.y; a0[q].z += s0*wv.z; a0[q].w += s0*wv.w;
        a1[q].x += s1*wv.x; a1[q].y += s1*wv.y; a1[q].z += s1*wv.z; a1[q].w += s1*wv.w;
      }
    }
  }
  float4* ob0 = (float4*)(buf + (size_t)r0*40);
  float4* ob1 = (float4*)(buf + (size_t)r1*40);
#pragma unroll
  for (int q=0;q<10;++q){ ob0[q] = a0[q]; ob1[q] = a1[q]; }
}

// ---------------- Phase 2: scan, 16 lanes per batch element ----------------
// lane bits: j = bits0-2 (hidden unit), p = bit3 (gate pair: p=0 -> {f,i},
// p=1 -> {u,o}), element-in-wave = bits4-5. ALL cross-lane traffic is DPP
// (no LDS/DS ops in the loop). h,c replicated across p (period-8 in the row).
__global__ __launch_bounds__(64) void qlstm_scan(
    const float* __restrict__ buf,
    const float* __restrict__ Wf, const float* __restrict__ Wi,
    const float* __restrict__ Wu, const float* __restrict__ Wo,
    const float* __restrict__ Wh2k,
    float* __restrict__ out,
    float* __restrict__ hstate, float* __restrict__ cstate,
    int t0, int tc, int initf, int lastf)
{
  int tid = threadIdx.x;          // 64
  int j = tid & 7;
  bool pb = (tid & 8) != 0;       // gate-pair select
  bool j4 = (j & 4) != 0;
  int b = blockIdx.x*4 + (tid >> 4);

  // slot A: p=0 -> f, p=1 -> u ; slot B: p=0 -> i, p=1 -> o
  const float* WA = pb ? Wu : Wf;
  const float* WB = pb ? Wo : Wi;
  float wrA[8], wrB[8], wkr[8];
#pragma unroll
  for (int s=0;s<8;++s){
    int k = (j + s) & 7;
    wrA[s] = WA[(64+k)*8 + j] * INV2PI;
    wrB[s] = WB[(64+k)*8 + j] * INV2PI;
    wkr[s] = Wh2k[k*8 + j] * INV4PI;
  }
  // slot-A activation constants (sigmoid for f, tanh for u)
  float kkA = pb ?  2.8853900817779268f : -1.4426950408889634f;
  float aaA = pb ? -2.0f : 1.0f;
  float bbA = pb ?  1.0f : 0.0f;

  float h, c;
  if (initf){ h = 0.f; c = 0.f; }
  else { h = hstate[b*8+j]; c = cstate[b*8+j]; }

  const float* bp = buf + (size_t)b*40;
  const size_t STRIDE = (size_t)BB*40;
  int oA = (pb?16:0) + j;     // gate A pre offset
  int oB = oA + 8;            // gate B pre offset
  int oK = 32 + j;            // kernel pre offset

  float xAq[4], xBq[4], xKq[4];
#pragma unroll
  for (int i=0;i<4;++i){
    const float* p_ = bp + (size_t)i*STRIDE;
    xAq[i]=p_[oA]; xBq[i]=p_[oB]; xKq[i]=p_[oK];
  }

  bool st = !pb;
  for (int tt4 = 0; tt4 < tc; tt4 += 4){
#pragma unroll
    for (int u=0; u<4; ++u){
      int tt = tt4 + u;
      float xA = xAq[u], xB = xBq[u], xK = xKq[u];
      int tn = tt + 4;
      if (tn < tc){
        const float* p_ = bp + (size_t)tn*STRIDE;
        xAq[u]=p_[oA]; xBq[u]=p_[oB]; xKq[u]=p_[oK];
      }

      // independent rotations of h (rotate-left-by-s within 16-row)
      float hr1 = DPPR(h,0x12F), hr2 = DPPR(h,0x12E), hr3 = DPPR(h,0x12D),
            hr4 = DPPR(h,0x12C), hr5 = DPPR(h,0x12B), hr6 = DPPR(h,0x12A),
            hr7 = DPPR(h,0x129);
      // matvecs (pre-scaled weights), 2-accumulator trees
      float aA0 =        h*wrA[0];  aA0 = fmaf(hr2,wrA[2],aA0); aA0 = fmaf(hr4,wrA[4],aA0); aA0 = fmaf(hr6,wrA[6],aA0);
      float aA1 =      hr1*wrA[1];  aA1 = fmaf(hr3,wrA[3],aA1); aA1 = fmaf(hr5,wrA[5],aA1); aA1 = fmaf(hr7,wrA[7],aA1);
      float aA = aA0 + aA1;
      float aB0 =        h*wrB[0];  aB0 = fmaf(hr2,wrB[2],aB0); aB0 = fmaf(hr4,wrB[4],aB0); aB0 = fmaf(hr6,wrB[6],aB0);
      float aB1 =      hr1*wrB[1];  aB1 = fmaf(hr3,wrB[3],aB1); aB1 = fmaf(hr5,wrB[5],aB1); aB1 = fmaf(hr7,wrB[7],aB1);
      float aB = aB0 + aB1;
      float aK0 =        h*wkr[0];  aK0 = fmaf(hr2,wkr[2],aK0); aK0 = fmaf(hr4,wkr[4],aK0); aK0 = fmaf(hr6,wkr[6],aK0);
      float aK1 =      hr1*wkr[1];  aK1 = fmaf(hr3,wkr[3],aK1); aK1 = fmaf(hr5,wkr[5],aK1); aK1 = fmaf(hr7,wkr[7],aK1);
      float aK = aK0 + aK1;

      // kernel weight: |prod_j cos(2pi*(aK - xK))| over 8-lane j-group, all DPP
      float kv = fcosrev(aK - xK);
      kv *= DPPR(kv,0xB1);                       // xor1 (quad_perm)
      kv *= DPPR(kv,0x4E);                       // xor2 (quad_perm)
      { float t4a = DPPR(kv,0x124), t4b = DPPR(kv,0x12C);  // xor4 via ror4/ror12
        kv *= (j4 ? t4a : t4b); }
      float wk = fabsf(kv);

      // per-slot qlayer: z = cos(2pi*(a + x)); gq = (j==0 ? prod z[1:] : cumprod z[0..j]) * wk
#define CUMQ(ZV, GQ) { \
      float zz = (ZV); \
      float pz = zz, s_; \
      s_ = DPPZ(pz,0x111); pz *= ((j>=1)? s_ : 1.0f); \
      s_ = DPPZ(pz,0x112); pz *= ((j>=2)? s_ : 1.0f); \
      s_ = DPPZ(pz,0x114); pz *= ((j>=4)? s_ : 1.0f); \
      float q = (j==0)? 1.0f : zz; \
      q *= DPPR(q,0xB1); \
      q *= DPPR(q,0x4E); \
      { float q4a = DPPR(q,0x124), q4b = DPPR(q,0x12C); q *= (j4 ? q4a : q4b); } \
      GQ = ((j==0)? q : pz) * wk; }

      float gA, gB;
      CUMQ(fcosrev(aA + xA), gA)
      CUMQ(fcosrev(aB + xB), gB)
#undef CUMQ

      // activations: slot A sigmoid/tanh via per-lane constants, slot B sigmoid
      float eA = fexp2(kkA*gA);
      float actA = fmaf(aaA, frcp(1.0f + eA), bbA);
      float eB = fexp2(-1.4426950408889634f*gB);
      float actB = frcp(1.0f + eB);

      // cross-pair gather via ror:8 (lane l <-> l^8)
      float gAo = DPPR(actA,0x128);
      float gBo = DPPR(actB,0x128);
      float fv = pb ? gAo  : actA;
      float uv = pb ? actA : gAo;
      float iv = pb ? gBo  : actB;
      float ov = pb ? actB : gBo;

      c = fmaf(fv, c, iv*uv);
      float ec = fexp2(2.8853900817779268f*c);
      float tch = fmaf(-2.0f, frcp(1.0f + ec), 1.0f);
      h = ov * tch;

      if (st) out[((size_t)(t0+tt)*BB + b)*8 + j] = h;
    }
  }

  if (st){
    if (lastf){
      out[(size_t)TT*BB*8 + (size_t)b*8 + j] = h;
      out[(size_t)TT*BB*8 + (size_t)BB*8 + (size_t)b*8 + j] = c;
    } else {
      hstate[b*8+j] = h;
      cstate[b*8+j] = c;
    }
  }
}

extern "C" void kernel_launch(void* const* d_in, const int* in_sizes, int n_in,
                              void* d_out, int out_size, void* d_ws, size_t ws_size,
                              hipStream_t stream)
{
  const float* x    = (const float*)d_in[0];
  const float* Wf   = (const float*)d_in[1];
  const float* bf   = (const float*)d_in[2];
  const float* thf  = (const float*)d_in[3];
  const float* Wi   = (const float*)d_in[4];
  const float* bi   = (const float*)d_in[5];
  const float* thi  = (const float*)d_in[6];
  const float* Wu   = (const float*)d_in[7];
  const float* bu   = (const float*)d_in[8];
  const float* thu  = (const float*)d_in[9];
  const float* Wo   = (const float*)d_in[10];
  const float* bo   = (const float*)d_in[11];
  const float* tho  = (const float*)d_in[12];
  const float* Wh2k = (const float*)d_in[13];
  const float* bh2k = (const float*)d_in[14];
  const float* Wi2k = (const float*)d_in[15];
  const float* bi2k = (const float*)d_in[16];
  float* out = (float*)d_out;

  // ws layout: hstate[8192 f] | cstate[8192 f] | xpre buf [tc][BB][40]
  float* hstate = (float*)d_ws;
  float* cstate = hstate + BB*8;
  float* buf    = cstate + BB*8;
  long long avail = (long long)ws_size - (long long)(2*BB*8*sizeof(float));
  const long long per_step = 40ll*BB*sizeof(float);  // 160 KiB per time step
  int tc = TT;
  while (tc > 4 && (long long)tc*per_step > avail) tc >>= 1;

  for (int t0 = 0; t0 < TT; t0 += tc){
    int cur = (TT - t0 < tc) ? (TT - t0) : tc;
    qlstm_proj<<<(cur*BB)/512, 256, 0, stream>>>(
        x + (size_t)t0*BB*64,
        Wf,bf,thf, Wi,bi,thi, Wu,bu,thu, Wo,bo,tho,
        bh2k, Wi2k, bi2k, buf);
    qlstm_scan<<<BB/4, 64, 0, stream>>>(
        buf, Wf, Wi, Wu, Wo, Wh2k, out, hstate, cstate,
        t0, cur, (t0==0)?1:0, (t0+cur>=TT)?1:0);
  }
}

// Round 5
// 308.149 us; speedup vs baseline: 1.4677x; 1.4677x over previous
//
#include <hip/hip_runtime.h>

#define TT 512
#define BB 1024
#define INV2PI 0.15915494309189535f
#define INV4PI 0.07957747154594767f

__device__ __forceinline__ float frcp(float x){ return __builtin_amdgcn_rcpf(x); }
// cos(2*pi*r) with r already in revolutions
__device__ __forceinline__ float fcosrev(float r){
  float rr = r - floorf(r);
  return __builtin_amdgcn_cosf(rr);
}

// DPP helpers (float through int). ror:n => lane l reads lane (l+16-n)%16.
#define DPPZ(v, ctrl) __int_as_float(__builtin_amdgcn_update_dpp(0, __float_as_int(v), (ctrl), 0xF, 0xF, true))
#define DPPR(v, ctrl) __int_as_float(__builtin_amdgcn_update_dpp(__float_as_int(v), __float_as_int(v), (ctrl), 0xF, 0xF, false))

// ---------------- Phase 1: xpre projection (pre-scaled to revolutions) ----
// xpre[t][b][c], c in [0,40):
//   c<32  (gate g=c>>3, jj=c&7):  (x@Wg[:64] + bg + thg) * INV2PI
//   c>=32 (kernel, jj=c-32):      (x@Wi2k + bi2k - bh2k) * INV4PI
__global__ __launch_bounds__(256) void qlstm_proj(
    const float* __restrict__ x,
    const float* __restrict__ Wf, const float* __restrict__ bf, const float* __restrict__ thf,
    const float* __restrict__ Wi, const float* __restrict__ bi, const float* __restrict__ thi,
    const float* __restrict__ Wu, const float* __restrict__ bu, const float* __restrict__ thu,
    const float* __restrict__ Wo, const float* __restrict__ bo, const float* __restrict__ tho,
    const float* __restrict__ bh2k,
    const float* __restrict__ Wi2k, const float* __restrict__ bi2k,
    float* __restrict__ buf)
{
  __shared__ float4 wl4[64][10];
  __shared__ float bias[40];
  int tid = threadIdx.x;
  float* wl = (float*)wl4;
  for (int idx = tid; idx < 64*40; idx += 256){
    int d = idx / 40, c = idx - d*40;
    float v;
    if (c < 32){
      int g = c >> 3, jj = c & 7;
      const float* W = (g==0)?Wf:((g==1)?Wi:((g==2)?Wu:Wo));
      v = W[d*8+jj] * INV2PI;
    } else {
      v = Wi2k[d*8 + (c-32)] * INV4PI;
    }
    wl[d*40+c] = v;
  }
  if (tid < 40){
    int c = tid; float v;
    if (c < 32){
      int g = c >> 3, jj = c & 7;
      const float* bp = (g==0)?bf:((g==1)?bi:((g==2)?bu:bo));
      const float* tp = (g==0)?thf:((g==1)?thi:((g==2)?thu:tho));
      v = (bp[jj] + tp[jj]) * INV2PI;
    } else {
      v = (bi2k[c-32] - bh2k[c-32]) * INV4PI;
    }
    bias[c] = v;
  }
  __syncthreads();

  long r0 = (long)blockIdx.x*512 + tid;
  long r1 = r0 + 256;
  const float4* x0 = (const float4*)(x + r0*64);
  const float4* x1 = (const float4*)(x + r1*64);
  float4 a0[10], a1[10];
#pragma unroll
  for (int q=0;q<10;++q){
    a0[q] = make_float4(bias[q*4+0],bias[q*4+1],bias[q*4+2],bias[q*4+3]);
    a1[q] = a0[q];
  }
#pragma unroll 1
  for (int d4=0; d4<16; ++d4){
    float4 xv0 = x0[d4];
    float4 xv1 = x1[d4];
#pragma unroll
    for (int dd=0; dd<4; ++dd){
      float s0 = (dd==0)?xv0.x:((dd==1)?xv0.y:((dd==2)?xv0.z:xv0.w));
      float s1 = (dd==0)?xv1.x:((dd==1)?xv1.y:((dd==2)?xv1.z:xv1.w));
#pragma unroll
      for (int q=0;q<10;++q){
        float4 wv = wl4[d4*4+dd][q];
        a0[q].x += s0*wv.x; a0[q].y += s0*wv.y; a0[q].z += s0*wv.z; a0[q].w += s0*wv.w;
        a1[q].x += s1*wv.x; a1[q].y += s1*wv.y; a1[q].z += s1*wv.z; a1[q].w += s1*wv.w;
      }
    }
  }
  float4* ob0 = (float4*)(buf + (size_t)r0*40);
  float4* ob1 = (float4*)(buf + (size_t)r1*40);
#pragma unroll
  for (int q=0;q<10;++q){ ob0[q] = a0[q]; ob1[q] = a1[q]; }
}

// ---------------- Phase 2: scan, 16 lanes per batch element ----------------
// lane bits: j = bits0-2 (hidden unit), p = bit3 (gate pair: p=0 -> {f,i},
// p=1 -> {u,o}), element-in-wave = bits4-5. All cross-lane via DPP.
// Activations: Pade rational forms (no v_exp on the chain):
//   sigmoid(x) = 0.5 + 0.5*tanh(x/2); tanh(y)~=y(15+y^2)/(15+6y^2)  (|y|<=1)
//   tanh(c)   ~= c(945+105c^2+c^4)/(945+420c^2+15c^4)               (|c|<=2.5)
__global__ __launch_bounds__(64) void qlstm_scan(
    const float* __restrict__ buf,
    const float* __restrict__ Wf, const float* __restrict__ Wi,
    const float* __restrict__ Wu, const float* __restrict__ Wo,
    const float* __restrict__ Wh2k,
    float* __restrict__ out,
    float* __restrict__ hstate, float* __restrict__ cstate,
    int t0, int tc, int initf, int lastf)
{
  int tid = threadIdx.x;          // 64
  int j = tid & 7;
  bool pb = (tid & 8) != 0;       // gate-pair select
  bool j4 = (j & 4) != 0;
  int b = blockIdx.x*4 + (tid >> 4);

  // slot A: p=0 -> f (sigmoid), p=1 -> u (tanh) ; slot B: p=0 -> i, p=1 -> o (sigmoid)
  const float* WA = pb ? Wu : Wf;
  const float* WB = pb ? Wo : Wi;
  float wrA[8], wrB[8], wkr[8];
#pragma unroll
  for (int s=0;s<8;++s){
    int k = (j + s) & 7;
    wrA[s] = WA[(64+k)*8 + j] * INV2PI;
    wrB[s] = WB[(64+k)*8 + j] * INV2PI;
    wkr[s] = Wh2k[k*8 + j] * INV4PI;
  }
  // slot-A activation constants: y = mA*x; act = fma(t, mA_inv..) ->
  // p=1 (tanh): y=x,  act = t
  // p=0 (sig) : y=x/2, act = 0.5*t + 0.5
  float mA = pb ? 1.0f : 0.5f;
  float bA = pb ? 0.0f : 0.5f;

  float h, c;
  if (initf){ h = 0.f; c = 0.f; }
  else { h = hstate[b*8+j]; c = cstate[b*8+j]; }

  const int S = BB*40;            // per-step stride (floats)
  int oA = b*40 + (pb?16:0) + j;  // gate A pre offset (floats)
  int oK = b*40 + 32 + j;         // kernel pre offset

  float xAq[4], xBq[4], xKq[4];
#pragma unroll
  for (int i=0;i<4;++i){
    xAq[i]=buf[oA + i*S]; xBq[i]=buf[oA + 8 + i*S]; xKq[i]=buf[oK + i*S];
  }
  int offA = oA + 4*S;            // prefetch cursor (row tt+4)
  int offK = oK + 4*S;
  int osto = (t0*BB + b)*8 + j;   // output cursor

  bool st = !pb;
  for (int tt4 = 0; tt4 < tc; tt4 += 4){
#pragma unroll
    for (int u=0; u<4; ++u){
      int tt = tt4 + u;
      float xA = xAq[u], xB = xBq[u], xK = xKq[u];
      // branch-free clamped prefetch (duplicate last row when past end; unused)
      xAq[u] = buf[offA]; xBq[u] = buf[offA + 8]; xKq[u] = buf[offK];
      int inc = (tt + 5 < tc) ? S : 0;
      offA += inc; offK += inc;

      // independent rotations of h (rotate-left-by-s within 16-row)
      float hr1 = DPPR(h,0x12F), hr2 = DPPR(h,0x12E), hr3 = DPPR(h,0x12D),
            hr4 = DPPR(h,0x12C), hr5 = DPPR(h,0x12B), hr6 = DPPR(h,0x12A),
            hr7 = DPPR(h,0x129);
      // matvecs (pre-scaled weights), 2-accumulator trees
      float aA0 =        h*wrA[0];  aA0 = fmaf(hr2,wrA[2],aA0); aA0 = fmaf(hr4,wrA[4],aA0); aA0 = fmaf(hr6,wrA[6],aA0);
      float aA1 =      hr1*wrA[1];  aA1 = fmaf(hr3,wrA[3],aA1); aA1 = fmaf(hr5,wrA[5],aA1); aA1 = fmaf(hr7,wrA[7],aA1);
      float aA = aA0 + aA1;
      float aB0 =        h*wrB[0];  aB0 = fmaf(hr2,wrB[2],aB0); aB0 = fmaf(hr4,wrB[4],aB0); aB0 = fmaf(hr6,wrB[6],aB0);
      float aB1 =      hr1*wrB[1];  aB1 = fmaf(hr3,wrB[3],aB1); aB1 = fmaf(hr5,wrB[5],aB1); aB1 = fmaf(hr7,wrB[7],aB1);
      float aB = aB0 + aB1;
      float aK0 =        h*wkr[0];  aK0 = fmaf(hr2,wkr[2],aK0); aK0 = fmaf(hr4,wkr[4],aK0); aK0 = fmaf(hr6,wkr[6],aK0);
      float aK1 =      hr1*wkr[1];  aK1 = fmaf(hr3,wkr[3],aK1); aK1 = fmaf(hr5,wkr[5],aK1); aK1 = fmaf(hr7,wkr[7],aK1);
      float aK = aK0 + aK1;

      // kernel weight: |prod_j cos(2pi*(aK - xK))| over 8-lane j-group, all DPP
      float kv = fcosrev(aK - xK);
      kv *= DPPR(kv,0xB1);                       // xor1 (quad_perm)
      kv *= DPPR(kv,0x4E);                       // xor2 (quad_perm)
      { float t4a = DPPR(kv,0x124), t4b = DPPR(kv,0x12C);  // xor4 via ror4/ror12
        kv *= (j4 ? t4a : t4b); }
      float wk = fabsf(kv);

      // per-slot qlayer: z = cos(2pi*(a + x)); gq = (j==0 ? prod z[1:] : cumprod z[0..j]) * wk
#define CUMQ(ZV, GQ) { \
      float zz = (ZV); \
      float pz = zz, s_; \
      s_ = DPPZ(pz,0x111); pz *= ((j>=1)? s_ : 1.0f); \
      s_ = DPPZ(pz,0x112); pz *= ((j>=2)? s_ : 1.0f); \
      s_ = DPPZ(pz,0x114); pz *= ((j>=4)? s_ : 1.0f); \
      float q = (j==0)? 1.0f : zz; \
      q *= DPPR(q,0xB1); \
      q *= DPPR(q,0x4E); \
      { float q4a = DPPR(q,0x124), q4b = DPPR(q,0x12C); q *= (j4 ? q4a : q4b); } \
      GQ = ((j==0)? q : pz) * wk; }

      float gA, gB;
      CUMQ(fcosrev(aA + xA), gA)
      CUMQ(fcosrev(aB + xB), gB)
#undef CUMQ

      // slot A: Pade(3,2) tanh core; y = mA*gA; act = mA*t + bA
      float yA = gA * mA;
      float y2A = yA * yA;
      float numA = y2A + 15.0f;
      float denA = fmaf(y2A, 6.0f, 15.0f);
      float tA = yA * numA * frcp(denA);
      float actA = fmaf(tA, mA + mA, bA) - (pb ? tA : 0.0f);
      // note: p=1: act = 2t - t = t ; p=0: act = t*1.0*... (mA+mA=1) -> t*1+0.5? 
      // p=0: mA+mA = 1.0 -> act = t + 0.5?? WRONG unless t already halved.
      // Fix: p=0 wants 0.5t+0.5: use fma(tA, mA, bA):
      actA = fmaf(tA, (pb ? 1.0f : 0.5f), bA);

      // slot B: sigmoid via same core with y = gB/2
      float yB = gB * 0.5f;
      float y2B = yB * yB;
      float numB = y2B + 15.0f;
      float denB = fmaf(y2B, 6.0f, 15.0f);
      float tB = yB * numB * frcp(denB);
      float actB = fmaf(tB, 0.5f, 0.5f);

      // cross-pair gather via ror:8 (lane l <-> l^8)
      float gAo = DPPR(actA,0x128);
      float gBo = DPPR(actB,0x128);
      float fv = pb ? gAo  : actA;
      float uv = pb ? actA : gAo;
      float iv = pb ? gBo  : actB;
      float ov = pb ? actB : gBo;

      c = fmaf(fv, c, iv*uv);
      // tanh(c) via Pade(5,4)
      float c2 = c * c;
      float n1 = c2 + 105.0f;
      float num = fmaf(c2, n1, 945.0f);
      float d1 = fmaf(c2, 15.0f, 420.0f);
      float den = fmaf(c2, d1, 945.0f);
      float tch = c * num * frcp(den);
      h = ov * tch;

      if (st) out[osto] = h;
      osto += BB*8;
    }
  }

  if (st){
    if (lastf){
      out[(size_t)TT*BB*8 + (size_t)b*8 + j] = h;
      out[(size_t)TT*BB*8 + (size_t)BB*8 + (size_t)b*8 + j] = c;
    } else {
      hstate[b*8+j] = h;
      cstate[b*8+j] = c;
    }
  }
}

extern "C" void kernel_launch(void* const* d_in, const int* in_sizes, int n_in,
                              void* d_out, int out_size, void* d_ws, size_t ws_size,
                              hipStream_t stream)
{
  const float* x    = (const float*)d_in[0];
  const float* Wf   = (const float*)d_in[1];
  const float* bf   = (const float*)d_in[2];
  const float* thf  = (const float*)d_in[3];
  const float* Wi   = (const float*)d_in[4];
  const float* bi   = (const float*)d_in[5];
  const float* thi  = (const float*)d_in[6];
  const float* Wu   = (const float*)d_in[7];
  const float* bu   = (const float*)d_in[8];
  const float* thu  = (const float*)d_in[9];
  const float* Wo   = (const float*)d_in[10];
  const float* bo   = (const float*)d_in[11];
  const float* tho  = (const float*)d_in[12];
  const float* Wh2k = (const float*)d_in[13];
  const float* bh2k = (const float*)d_in[14];
  const float* Wi2k = (const float*)d_in[15];
  const float* bi2k = (const float*)d_in[16];
  float* out = (float*)d_out;

  // ws layout: hstate[8192 f] | cstate[8192 f] | xpre buf [tc][BB][40]
  float* hstate = (float*)d_ws;
  float* cstate = hstate + BB*8;
  float* buf    = cstate + BB*8;
  long long avail = (long long)ws_size - (long long)(2*BB*8*sizeof(float));
  const long long per_step = 40ll*BB*sizeof(float);  // 160 KiB per time step
  int tc = TT;
  while (tc > 4 && (long long)tc*per_step > avail) tc >>= 1;

  for (int t0 = 0; t0 < TT; t0 += tc){
    int cur = (TT - t0 < tc) ? (TT - t0) : tc;
    qlstm_proj<<<(cur*BB)/512, 256, 0, stream>>>(
        x + (size_t)t0*BB*64,
        Wf,bf,thf, Wi,bi,thi, Wu,bu,thu, Wo,bo,tho,
        bh2k, Wi2k, bi2k, buf);
    qlstm_scan<<<BB/4, 64, 0, stream>>>(
        buf, Wf, Wi, Wu, Wo, Wh2k, out, hstate, cstate,
        t0, cur, (t0==0)?1:0, (t0+cur>=TT)?1:0);
  }
}